// Round 1
// baseline (1361.293 us; speedup 1.0000x reference)
//
#include <hip/hip_runtime.h>
#include <hip/hip_bf16.h>
#include <cstdint>

#define BB 64
#define TT 2048
#define FD 256
#define UU 32

// ---------------------------------------------------------------------------
// Kernel 1: pot[b,t,u] = dot(x[b,t,:], K[:,u]) + bias[u] (+ boundaries)
// ---------------------------------------------------------------------------
__global__ __launch_bounds__(256) void potentials_kernel(
    const float* __restrict__ x, const float* __restrict__ K,
    const float* __restrict__ bias, const float* __restrict__ lb,
    const float* __restrict__ rb, float* __restrict__ pot)
{
    __shared__ float Ks[FD * UU];   // 32 KB, [f][u] layout: bank = u, conflict-free
    __shared__ float xs[16 * FD];   // 16 KB, 16 rows per tile

    const int tid = threadIdx.x;
    for (int i = tid; i < FD * UU; i += 256) Ks[i] = K[i];

    const int u = tid & 31;
    const int g = tid >> 5;               // 0..7
    const float bu = bias[u];
    const float lu = lb[u];
    const float ru = rb[u];

    const int tiles = (BB * TT) / 16;     // 8192
    for (int tile = blockIdx.x; tile < tiles; tile += gridDim.x) {
        const int row0 = tile * 16;
        __syncthreads();                  // protect xs from previous readers
        {
            const float4* src = (const float4*)(x + (size_t)row0 * FD);
            float4* dst = (float4*)xs;
            #pragma unroll
            for (int i = 0; i < 4; ++i) dst[tid + i * 256] = src[tid + i * 256];
        }
        __syncthreads();

        float acc0 = 0.f, acc1 = 0.f;
        #pragma unroll
        for (int f = 0; f < FD; f += 4) {
            const float4 xa = *(const float4*)&xs[g * FD + f];
            const float4 xb = *(const float4*)&xs[(g + 8) * FD + f];
            const float k0 = Ks[(f + 0) * UU + u];
            const float k1 = Ks[(f + 1) * UU + u];
            const float k2 = Ks[(f + 2) * UU + u];
            const float k3 = Ks[(f + 3) * UU + u];
            acc0 += xa.x * k0; acc0 += xa.y * k1; acc0 += xa.z * k2; acc0 += xa.w * k3;
            acc1 += xb.x * k0; acc1 += xb.y * k1; acc1 += xb.z * k2; acc1 += xb.w * k3;
        }

        const int ra = row0 + g;
        const int rbw = row0 + g + 8;
        const int ta = ra & (TT - 1);
        const int tb = rbw & (TT - 1);
        float adda = bu + (ta == 0 ? lu : 0.f) + (ta == TT - 1 ? ru : 0.f);
        float addb = bu + (tb == 0 ? lu : 0.f) + (tb == TT - 1 ? ru : 0.f);
        pot[(size_t)ra * UU + u]  = acc0 + adda;
        pot[(size_t)rbw * UU + u] = acc1 + addb;
    }
}

// ---------------------------------------------------------------------------
// Kernel 2: per-batch Viterbi forward + windowed backtrack.
// One wave (64 threads) per batch. Lane = (u = lane&31, h = lane>>5).
// State distributed: lanes u and u+32 both hold cur[u].
// bp (uint8) kept entirely in LDS. Survivor-origin compression every 64 steps
// into registers E[32] -> O(32) boundary walk + 32 parallel window walks.
// ---------------------------------------------------------------------------
__global__ __launch_bounds__(64) void viterbi_kernel(
    const float* __restrict__ pot, const float* __restrict__ chain,
    int* __restrict__ out)
{
    __shared__ unsigned char bp[(TT - 1) * UU];   // 65504 B

    const int lane = threadIdx.x;
    const int u = lane & 31;
    const int h = lane >> 5;
    const int b = blockIdx.x;
    const float* pb = pot + (size_t)b * TT * UU;

    // chain column fragment: cc[i] = chain[16h+i][u]
    float cc[16];
    #pragma unroll
    for (int i = 0; i < 16; ++i) cc[i] = chain[(16 * h + i) * UU + u];

    float cur = pb[u];        // t = 0 (includes bias + left boundary)
    int orig = u;             // survivor origin pointer
    int E[32];

    float p = pb[UU + u];     // pot for t = 1 (prefetched)

    #pragma unroll
    for (int w = 0; w < 32; ++w) {
        const int t0 = (w == 0) ? 1 : w * 64;
        const int t1 = (w + 1) * 64;
        #pragma unroll 1
        for (int t = t0; t < t1; ++t) {
            // prefetch next pot one step ahead (hide L2/HBM latency)
            const int tn = (t + 1 < TT) ? (t + 1) : t;
            const float pnext = pb[tn * UU + u];

            // reduce over v in [16h, 16h+16), ascending, strict > (first-max tie)
            float best;
            int bestv;
            {
                const float sv = __shfl(cur, 16 * h, 64);
                best = sv + cc[0];
                bestv = 16 * h;
            }
            #pragma unroll
            for (int i = 1; i < 16; ++i) {
                const float sv = __shfl(cur, 16 * h + i, 64);
                const float sc = sv + cc[i];
                if (sc > best) { best = sc; bestv = 16 * h + i; }
            }
            // combine halves; on tie prefer lower-v half (h==0)
            const float ob = __shfl(best, lane ^ 32, 64);
            const int obv = __shfl(bestv, lane ^ 32, 64);
            const bool take = (h == 0) ? (ob > best) : (ob >= best);
            const float m = take ? ob : best;
            const int mv = take ? obv : bestv;

            cur = m + p;
            orig = __shfl(orig, mv, 64);     // compose survivor origin
            if (h == 0) bp[(t - 1) * UU + u] = (unsigned char)mv;
            p = pnext;
        }
        E[w] = orig;      // tag at t = 64w-1 (or 0) on best path to (64w+63, u)
        orig = u;
    }

    // last_tag = argmax_u cur, smallest u on tie
    float bv = cur;
    int bi = u;
    #pragma unroll
    for (int mask = 16; mask >= 1; mask >>= 1) {
        const float ov = __shfl_xor(bv, mask, 64);
        const int oi = __shfl_xor(bi, mask, 64);
        if (ov > bv || (ov == bv && oi < bi)) { bv = ov; bi = oi; }
    }
    int bt = bi;          // uniform across wave

    // boundary walk: b_tag[w] = tag at t = 64w+63
    int my_btag = 0;
    #pragma unroll
    for (int w = 31; w >= 0; --w) {
        if (lane == w) my_btag = bt;
        bt = __shfl(E[w], bt, 64);
    }

    // parallel window walks: lane w covers t in [64w, 64w+63]
    if (lane < 32) {
        const int w = lane;
        int t = w * 64 + 63;
        int tag = my_btag;
        int* ob = out + (size_t)b * TT;
        ob[t] = tag;
        #pragma unroll 1
        for (; t >= w * 64 + 1; --t) {
            tag = bp[(t - 1) * UU + tag];
            ob[t - 1] = tag;
        }
    }
}

// ---------------------------------------------------------------------------
extern "C" void kernel_launch(void* const* d_in, const int* in_sizes, int n_in,
                              void* d_out, int out_size, void* d_ws, size_t ws_size,
                              hipStream_t stream)
{
    const float* x     = (const float*)d_in[0];
    const float* K     = (const float*)d_in[1];
    const float* bias  = (const float*)d_in[2];
    const float* chain = (const float*)d_in[3];
    const float* lb    = (const float*)d_in[4];
    const float* rb    = (const float*)d_in[5];
    int* out = (int*)d_out;
    float* pot = (float*)d_ws;     // 64*2048*32*4 = 16 MB scratch

    potentials_kernel<<<1024, 256, 0, stream>>>(x, K, bias, lb, rb, pot);
    viterbi_kernel<<<BB, 64, 0, stream>>>(pot, chain, out);
}

// Round 2
// 707.243 us; speedup vs baseline: 1.9248x; 1.9248x over previous
//
#include <hip/hip_runtime.h>
#include <hip/hip_bf16.h>
#include <cstdint>

#define BB 64
#define TT 2048
#define FD 256
#define UU 32

// ---------------------------------------------------------------------------
// Kernel 1: pot[b,t,u] = dot(x[b,t,:], K[:,u]) + bias[u] (+ boundaries)
// ---------------------------------------------------------------------------
__global__ __launch_bounds__(256) void potentials_kernel(
    const float* __restrict__ x, const float* __restrict__ K,
    const float* __restrict__ bias, const float* __restrict__ lb,
    const float* __restrict__ rb, float* __restrict__ pot)
{
    __shared__ float Ks[FD * UU];   // 32 KB, [f][u]: bank = u, conflict-free
    __shared__ float xs[16 * FD];   // 16 KB, 16 rows per tile

    const int tid = threadIdx.x;
    for (int i = tid; i < FD * UU; i += 256) Ks[i] = K[i];

    const int u = tid & 31;
    const int g = tid >> 5;               // 0..7
    const float bu = bias[u];
    const float lu = lb[u];
    const float ru = rb[u];

    const int tiles = (BB * TT) / 16;     // 8192
    for (int tile = blockIdx.x; tile < tiles; tile += gridDim.x) {
        const int row0 = tile * 16;
        __syncthreads();
        {
            const float4* src = (const float4*)(x + (size_t)row0 * FD);
            float4* dst = (float4*)xs;
            #pragma unroll
            for (int i = 0; i < 4; ++i) dst[tid + i * 256] = src[tid + i * 256];
        }
        __syncthreads();

        float acc0 = 0.f, acc1 = 0.f;
        #pragma unroll
        for (int f = 0; f < FD; f += 4) {
            const float4 xa = *(const float4*)&xs[g * FD + f];
            const float4 xb = *(const float4*)&xs[(g + 8) * FD + f];
            const float k0 = Ks[(f + 0) * UU + u];
            const float k1 = Ks[(f + 1) * UU + u];
            const float k2 = Ks[(f + 2) * UU + u];
            const float k3 = Ks[(f + 3) * UU + u];
            acc0 += xa.x * k0; acc0 += xa.y * k1; acc0 += xa.z * k2; acc0 += xa.w * k3;
            acc1 += xb.x * k0; acc1 += xb.y * k1; acc1 += xb.z * k2; acc1 += xb.w * k3;
        }

        const int ra = row0 + g;
        const int rbw = row0 + g + 8;
        const int ta = ra & (TT - 1);
        const int tb = rbw & (TT - 1);
        float adda = bu + (ta == 0 ? lu : 0.f) + (ta == TT - 1 ? ru : 0.f);
        float addb = bu + (tb == 0 ? lu : 0.f) + (tb == TT - 1 ? ru : 0.f);
        pot[(size_t)ra * UU + u]  = acc0 + adda;
        pot[(size_t)rbw * UU + u] = acc1 + addb;
    }
}

// ---------------------------------------------------------------------------
// Kernel 2: values-only serial forward. 16 waves/block (one batch per wave),
// grid 4 -> 4 waves/SIMD for latency hiding. Checkpoints state every 64 steps:
// chk[b][w][u] = state at t = 64w-1 (w=1..31), chk[b][32] = state at t=2047.
// ---------------------------------------------------------------------------
__global__ __launch_bounds__(1024, 4) void vit_values_kernel(
    const float* __restrict__ pot, const float* __restrict__ chain,
    float* __restrict__ chk)
{
    __shared__ float lm[16 * 32];

    const int tid  = threadIdx.x;
    const int wv   = tid >> 6;
    const int lane = tid & 63;
    const int u    = lane & 31;
    const int h    = lane >> 5;
    const int hbase = 16 * h;
    const int b    = blockIdx.x * 16 + wv;
    const float* pb = pot + (size_t)b * TT * UU;
    float* mbuf = &lm[wv * 32];

    float cc[16];
    #pragma unroll
    for (int i = 0; i < 16; ++i) cc[i] = chain[(hbase + i) * UU + u];

    float s[16];
    #pragma unroll
    for (int i = 0; i < 16; ++i) s[i] = pb[hbase + i];   // state at t=0

    float pr[16], pn[16];
    #pragma unroll
    for (int j = 0; j < 16; ++j) pr[j] = pb[(1 + j) * UU + u];

    auto step = [&](float potv, bool ckpt, int wck) {
        float a[16];
        #pragma unroll
        for (int i = 0; i < 16; ++i) a[i] = s[i] + cc[i];
        float m8[8];
        #pragma unroll
        for (int i = 0; i < 8; ++i) m8[i] = fmaxf(a[2*i], a[2*i+1]);
        float m4[4];
        #pragma unroll
        for (int i = 0; i < 4; ++i) m4[i] = fmaxf(m8[2*i], m8[2*i+1]);
        const float m2a = fmaxf(m4[0], m4[1]);
        const float m2b = fmaxf(m4[2], m4[3]);
        const float pm = fmaxf(m2a, m2b);

        const float q = pm + potv;
        const float o = __shfl_xor(q, 32, 64);
        const float mm = fmaxf(q, o);          // == rnd(max_all + pot) bitwise

        mbuf[u] = mm;                          // lanes u and u+32 write same value
        if (ckpt && lane < 32)
            chk[((size_t)b * 33 + wck) * UU + u] = mm;

        const float4 v0 = *(const float4*)&mbuf[hbase + 0];
        const float4 v1 = *(const float4*)&mbuf[hbase + 4];
        const float4 v2 = *(const float4*)&mbuf[hbase + 8];
        const float4 v3 = *(const float4*)&mbuf[hbase + 12];
        s[0]=v0.x; s[1]=v0.y; s[2]=v0.z;  s[3]=v0.w;
        s[4]=v1.x; s[5]=v1.y; s[6]=v1.z;  s[7]=v1.w;
        s[8]=v2.x; s[9]=v2.y; s[10]=v2.z; s[11]=v2.w;
        s[12]=v3.x; s[13]=v3.y; s[14]=v3.z; s[15]=v3.w;
    };

    for (int g = 0; g < 127; ++g) {
        #pragma unroll
        for (int j = 0; j < 16; ++j) {
            int tp = 16 * (g + 1) + 1 + j;
            if (tp > TT - 1) tp = TT - 1;
            pn[j] = pb[tp * UU + u];
        }
        const bool ck = ((g & 3) == 3);
        const int wck = (g >> 2) + 1;
        #pragma unroll
        for (int j = 0; j < 16; ++j)
            step(pr[j], ck && (j == 14), wck);
        #pragma unroll
        for (int j = 0; j < 16; ++j) pr[j] = pn[j];
    }
    // epilogue: g = 127, steps t = 2033..2047 (j = 0..14), checkpoint w=32 at j==14
    #pragma unroll
    for (int j = 0; j < 15; ++j)
        step(pr[j], j == 14, 32);
}

// ---------------------------------------------------------------------------
// Kernel 3: parallel window recompute. Block (w, b): steps t in
// [max(1,64w), 64w+64) from bit-exact checkpoint; emits bp bytes (global) and
// survivor map M[w][u] = tag at window start for best path ending (64w+63, u).
// ---------------------------------------------------------------------------
__global__ __launch_bounds__(64) void vit_window_kernel(
    const float* __restrict__ pot, const float* __restrict__ chain,
    const float* __restrict__ chk, unsigned char* __restrict__ Mg,
    unsigned char* __restrict__ bpg)
{
    __shared__ float potL[64 * 32];   // 8 KB: pot rows 64w .. 64w+63
    __shared__ float mbuf[32];

    const int lane = threadIdx.x;
    const int u = lane & 31;
    const int h = lane >> 5;
    const int hbase = 16 * h;
    const int w = blockIdx.x;
    const int b = blockIdx.y;
    const float* pb = pot + (size_t)b * TT * UU;
    const int r0 = 64 * w;

    {
        const float4* src = (const float4*)(pb + (size_t)r0 * UU);
        float4* dst = (float4*)potL;
        #pragma unroll
        for (int k = 0; k < 8; ++k) dst[lane + 64 * k] = src[lane + 64 * k];
    }
    __syncthreads();

    float cc[16];
    #pragma unroll
    for (int i = 0; i < 16; ++i) cc[i] = chain[(hbase + i) * UU + u];

    float s[16];
    if (w == 0) {
        #pragma unroll
        for (int i = 0; i < 16; ++i) s[i] = potL[hbase + i];          // state t=0
    } else {
        #pragma unroll
        for (int i = 0; i < 16; ++i) s[i] = chk[((size_t)b * 33 + w) * UU + hbase + i];
    }

    int orig = u;
    unsigned char* bb = bpg + (size_t)b * (TT - 1) * UU;

    const int tl0 = (w == 0) ? 1 : 0;
    #pragma unroll 1
    for (int tl = tl0; tl < 64; ++tl) {
        const int t = r0 + tl;
        const float potv = potL[tl * UU + u];

        float a[16];
        #pragma unroll
        for (int i = 0; i < 16; ++i) a[i] = s[i] + cc[i];

        // first-occurrence argmax: pairwise tree, right wins only if strictly >
        float v8[8]; int i8[8];
        #pragma unroll
        for (int i = 0; i < 8; ++i) {
            const bool c = a[2*i+1] > a[2*i];
            v8[i] = c ? a[2*i+1] : a[2*i];
            i8[i] = c ? (2*i+1) : (2*i);
        }
        float v4[4]; int i4[4];
        #pragma unroll
        for (int i = 0; i < 4; ++i) {
            const bool c = v8[2*i+1] > v8[2*i];
            v4[i] = c ? v8[2*i+1] : v8[2*i];
            i4[i] = c ? i8[2*i+1] : i8[2*i];
        }
        float v2[2]; int i2[2];
        #pragma unroll
        for (int i = 0; i < 2; ++i) {
            const bool c = v4[2*i+1] > v4[2*i];
            v2[i] = c ? v4[2*i+1] : v4[2*i];
            i2[i] = c ? i4[2*i+1] : i4[2*i];
        }
        const bool cf = v2[1] > v2[0];
        const float pv = cf ? v2[1] : v2[0];
        const int pidx = hbase + (cf ? i2[1] : i2[0]);

        const float opv = __shfl_xor(pv, 32, 64);
        const int   opi = __shfl_xor(pidx, 32, 64);
        const bool take = h ? (opv >= pv) : (opv > pv);   // tie -> lower half
        const int  mv   = take ? opi : pidx;
        const float mm  = fmaxf(pv, opv) + potv;

        if (h == 0) bb[(size_t)(t - 1) * UU + u] = (unsigned char)mv;
        orig = __shfl(orig, mv, 64);

        mbuf[u] = mm;
        const float4 x0 = *(const float4*)&mbuf[hbase + 0];
        const float4 x1 = *(const float4*)&mbuf[hbase + 4];
        const float4 x2 = *(const float4*)&mbuf[hbase + 8];
        const float4 x3 = *(const float4*)&mbuf[hbase + 12];
        s[0]=x0.x; s[1]=x0.y; s[2]=x0.z;  s[3]=x0.w;
        s[4]=x1.x; s[5]=x1.y; s[6]=x1.z;  s[7]=x1.w;
        s[8]=x2.x; s[9]=x2.y; s[10]=x2.z; s[11]=x2.w;
        s[12]=x3.x; s[13]=x3.y; s[14]=x3.z; s[15]=x3.w;
    }

    if (h == 0) Mg[(size_t)b * 1024 + w * UU + u] = (unsigned char)orig;
}

// ---------------------------------------------------------------------------
// Kernel 4: per-batch boundary walk over M + 32 parallel window backtracks.
// ---------------------------------------------------------------------------
__global__ __launch_bounds__(64) void vit_backtrack_kernel(
    const float* __restrict__ chk, const unsigned char* __restrict__ Mg,
    const unsigned char* __restrict__ bpg, int* __restrict__ out)
{
    __shared__ unsigned char Ml[1024];
    __shared__ int tagw[32];

    const int lane = threadIdx.x;
    const int b = blockIdx.x;

    ((int4*)Ml)[lane] = ((const int4*)(Mg + (size_t)b * 1024))[lane];

    // last_tag = argmax_u chk[b][32][u], smallest u on tie
    float fv = (lane < 32) ? chk[((size_t)b * 33 + 32) * UU + lane] : -INFINITY;
    int fi = lane & 31;
    #pragma unroll
    for (int mask = 16; mask >= 1; mask >>= 1) {
        const float ov = __shfl_xor(fv, mask, 64);
        const int oi = __shfl_xor(fi, mask, 64);
        if (ov > fv || (ov == fv && oi < fi)) { fv = ov; fi = oi; }
    }
    int bt = __shfl(fi, 0, 64);

    __syncthreads();
    #pragma unroll 1
    for (int w = 31; w >= 0; --w) {
        if (lane == 0) tagw[w] = bt;         // tag at t = 64w+63
        bt = Ml[w * 32 + bt];                // -> tag at 64(w-1)+63
    }
    __syncthreads();

    if (lane < 32) {
        const int w = lane;
        int tag = tagw[w];
        int t = w * 64 + 63;
        int* ob = out + (size_t)b * TT;
        const unsigned char* bb = bpg + (size_t)b * (TT - 1) * UU;
        ob[t] = tag;
        #pragma unroll 1
        for (; t >= w * 64 + 1; --t) {
            tag = bb[(size_t)(t - 1) * UU + tag];
            ob[t - 1] = tag;
        }
    }
}

// ---------------------------------------------------------------------------
extern "C" void kernel_launch(void* const* d_in, const int* in_sizes, int n_in,
                              void* d_out, int out_size, void* d_ws, size_t ws_size,
                              hipStream_t stream)
{
    const float* x     = (const float*)d_in[0];
    const float* K     = (const float*)d_in[1];
    const float* bias  = (const float*)d_in[2];
    const float* chain = (const float*)d_in[3];
    const float* lb    = (const float*)d_in[4];
    const float* rb    = (const float*)d_in[5];
    int* out = (int*)d_out;

    float* pot = (float*)d_ws;                          // 16 MB
    float* chk = pot + (size_t)BB * TT * UU;            // 64*33*32 floats = 264 KB
    unsigned char* Mg  = (unsigned char*)(chk + (size_t)BB * 33 * UU);  // 64 KB
    unsigned char* bpg = Mg + (size_t)BB * 32 * UU;     // 64*2047*32 = 4 MB

    potentials_kernel<<<1024, 256, 0, stream>>>(x, K, bias, lb, rb, pot);
    vit_values_kernel<<<4, 1024, 0, stream>>>(pot, chain, chk);
    vit_window_kernel<<<dim3(32, BB), 64, 0, stream>>>(pot, chain, chk, Mg, bpg);
    vit_backtrack_kernel<<<BB, 64, 0, stream>>>(chk, Mg, bpg, out);
}

// Round 3
// 578.811 us; speedup vs baseline: 2.3519x; 1.2219x over previous
//
#include <hip/hip_runtime.h>
#include <hip/hip_bf16.h>
#include <cstdint>

#define BB 64
#define TT 2048
#define FD 256
#define UU 32

// ---------------------------------------------------------------------------
// Kernel 1: pot[b,t,u] = dot(x[b,t,:], K[:,u]) + bias[u] (+ boundaries)
// ---------------------------------------------------------------------------
__global__ __launch_bounds__(256) void potentials_kernel(
    const float* __restrict__ x, const float* __restrict__ K,
    const float* __restrict__ bias, const float* __restrict__ lb,
    const float* __restrict__ rb, float* __restrict__ pot)
{
    __shared__ float Ks[FD * UU];   // 32 KB, [f][u]: bank = u, conflict-free
    __shared__ float xs[16 * FD];   // 16 KB, 16 rows per tile

    const int tid = threadIdx.x;
    for (int i = tid; i < FD * UU; i += 256) Ks[i] = K[i];

    const int u = tid & 31;
    const int g = tid >> 5;               // 0..7
    const float bu = bias[u];
    const float lu = lb[u];
    const float ru = rb[u];

    const int tiles = (BB * TT) / 16;     // 8192
    for (int tile = blockIdx.x; tile < tiles; tile += gridDim.x) {
        const int row0 = tile * 16;
        __syncthreads();
        {
            const float4* src = (const float4*)(x + (size_t)row0 * FD);
            float4* dst = (float4*)xs;
            #pragma unroll
            for (int i = 0; i < 4; ++i) dst[tid + i * 256] = src[tid + i * 256];
        }
        __syncthreads();

        float acc0 = 0.f, acc1 = 0.f;
        #pragma unroll
        for (int f = 0; f < FD; f += 4) {
            const float4 xa = *(const float4*)&xs[g * FD + f];
            const float4 xb = *(const float4*)&xs[(g + 8) * FD + f];
            const float k0 = Ks[(f + 0) * UU + u];
            const float k1 = Ks[(f + 1) * UU + u];
            const float k2 = Ks[(f + 2) * UU + u];
            const float k3 = Ks[(f + 3) * UU + u];
            acc0 += xa.x * k0; acc0 += xa.y * k1; acc0 += xa.z * k2; acc0 += xa.w * k3;
            acc1 += xb.x * k0; acc1 += xb.y * k1; acc1 += xb.z * k2; acc1 += xb.w * k3;
        }

        const int ra = row0 + g;
        const int rbw = row0 + g + 8;
        const int ta = ra & (TT - 1);
        const int tb = rbw & (TT - 1);
        float adda = bu + (ta == 0 ? lu : 0.f) + (ta == TT - 1 ? ru : 0.f);
        float addb = bu + (tb == 0 ? lu : 0.f) + (tb == TT - 1 ? ru : 0.f);
        pot[(size_t)ra * UU + u]  = acc0 + adda;
        pot[(size_t)rbw * UU + u] = acc1 + addb;
    }
}

// ---------------------------------------------------------------------------
// Kernel 2: values-only serial forward, latency-optimized.
// One wave per block, 2 batches per wave (half-wave h = batch). Each lane
// holds the full 32-state in registers + chain column cc[v] = chain[v][u].
// Step: 32 adds + exact max tree + pot, then one LDS roundtrip to
// redistribute the new state (broadcast reads, conflict-free).
// Checkpoints: chk[b][w][u] = state at t = 64w-1 (w=1..31), chk[b][32] = t=2047.
// ---------------------------------------------------------------------------
__global__ __launch_bounds__(64) void vit_values_kernel(
    const float* __restrict__ pot, const float* __restrict__ chain,
    float* __restrict__ chk)
{
    __shared__ __align__(16) float mbuf[64];

    const int lane = threadIdx.x;
    const int u = lane & 31;
    const int h = lane >> 5;
    const int b = blockIdx.x * 2 + h;
    const float* pb = pot + (size_t)b * TT * UU;
    const int h32 = h * 32;

    float cc[32];
    #pragma unroll
    for (int v = 0; v < 32; ++v) cc[v] = chain[v * UU + u];

    float s[32];
    #pragma unroll
    for (int v = 0; v < 32; ++v) s[v] = pb[v];   // state at t=0

    auto step = [&](float potv, int t) {
        float a[32];
        #pragma unroll
        for (int v = 0; v < 32; ++v) a[v] = s[v] + cc[v];
        float m16[16];
        #pragma unroll
        for (int i = 0; i < 16; ++i) m16[i] = fmaxf(a[2*i], a[2*i+1]);
        float m8[8];
        #pragma unroll
        for (int i = 0; i < 8; ++i) m8[i] = fmaxf(m16[2*i], m16[2*i+1]);
        float m4[4];
        #pragma unroll
        for (int i = 0; i < 4; ++i) m4[i] = fmaxf(m8[2*i], m8[2*i+1]);
        const float pm = fmaxf(fmaxf(m4[0], m4[1]), fmaxf(m4[2], m4[3]));
        const float mm = pm + potv;            // bit-exact: rnd(max_all + pot)

        mbuf[h32 + u] = mm;                    // DS ops in-order within a wave

        if ((t & 63) == 63) {
            const int wck = (t >> 6) + 1;
            chk[((size_t)b * 33 + wck) * UU + u] = mm;
        }

        const float4 x0 = *(const float4*)&mbuf[h32 + 0];
        const float4 x1 = *(const float4*)&mbuf[h32 + 4];
        const float4 x2 = *(const float4*)&mbuf[h32 + 8];
        const float4 x3 = *(const float4*)&mbuf[h32 + 12];
        const float4 x4 = *(const float4*)&mbuf[h32 + 16];
        const float4 x5 = *(const float4*)&mbuf[h32 + 20];
        const float4 x6 = *(const float4*)&mbuf[h32 + 24];
        const float4 x7 = *(const float4*)&mbuf[h32 + 28];
        s[0]=x0.x;  s[1]=x0.y;  s[2]=x0.z;  s[3]=x0.w;
        s[4]=x1.x;  s[5]=x1.y;  s[6]=x1.z;  s[7]=x1.w;
        s[8]=x2.x;  s[9]=x2.y;  s[10]=x2.z; s[11]=x2.w;
        s[12]=x3.x; s[13]=x3.y; s[14]=x3.z; s[15]=x3.w;
        s[16]=x4.x; s[17]=x4.y; s[18]=x4.z; s[19]=x4.w;
        s[20]=x5.x; s[21]=x5.y; s[22]=x5.z; s[23]=x5.w;
        s[24]=x6.x; s[25]=x6.y; s[26]=x6.z; s[27]=x6.w;
        s[28]=x7.x; s[29]=x7.y; s[30]=x7.z; s[31]=x7.w;
    };

    float pr[8], pn[8];
    #pragma unroll
    for (int j = 0; j < 8; ++j) pr[j] = pb[(1 + j) * UU + u];

    // groups of 8 steps: g covers t = 1+8g .. 8+8g, g = 0..254 (t = 1..2040)
    #pragma unroll 1
    for (int g = 0; g < 255; ++g) {
        #pragma unroll
        for (int j = 0; j < 8; ++j) {
            int tp = 9 + 8 * g + j;
            if (tp > TT - 1) tp = TT - 1;
            pn[j] = pb[tp * UU + u];
        }
        const int t0 = 1 + 8 * g;
        #pragma unroll
        for (int j = 0; j < 8; ++j)
            step(pr[j], t0 + j);
        #pragma unroll
        for (int j = 0; j < 8; ++j) pr[j] = pn[j];
    }
    // tail: t = 2041..2047 (includes final checkpoint wck = 32 at t = 2047)
    #pragma unroll
    for (int j = 0; j < 7; ++j)
        step(pr[j], 2041 + j);
}

// ---------------------------------------------------------------------------
// Kernel 3: parallel window recompute. Block (w, b): steps t in
// [max(1,64w), 64w+64) from bit-exact checkpoint; emits bp bytes (global) and
// survivor map M[w][u] = tag at window start for best path ending (64w+63, u).
// ---------------------------------------------------------------------------
__global__ __launch_bounds__(64) void vit_window_kernel(
    const float* __restrict__ pot, const float* __restrict__ chain,
    const float* __restrict__ chk, unsigned char* __restrict__ Mg,
    unsigned char* __restrict__ bpg)
{
    __shared__ float potL[64 * 32];   // 8 KB: pot rows 64w .. 64w+63
    __shared__ float mbuf[32];

    const int lane = threadIdx.x;
    const int u = lane & 31;
    const int h = lane >> 5;
    const int hbase = 16 * h;
    const int w = blockIdx.x;
    const int b = blockIdx.y;
    const float* pb = pot + (size_t)b * TT * UU;
    const int r0 = 64 * w;

    {
        const float4* src = (const float4*)(pb + (size_t)r0 * UU);
        float4* dst = (float4*)potL;
        #pragma unroll
        for (int k = 0; k < 8; ++k) dst[lane + 64 * k] = src[lane + 64 * k];
    }
    __syncthreads();

    float cc[16];
    #pragma unroll
    for (int i = 0; i < 16; ++i) cc[i] = chain[(hbase + i) * UU + u];

    float s[16];
    if (w == 0) {
        #pragma unroll
        for (int i = 0; i < 16; ++i) s[i] = potL[hbase + i];          // state t=0
    } else {
        #pragma unroll
        for (int i = 0; i < 16; ++i) s[i] = chk[((size_t)b * 33 + w) * UU + hbase + i];
    }

    int orig = u;
    unsigned char* bb = bpg + (size_t)b * (TT - 1) * UU;

    const int tl0 = (w == 0) ? 1 : 0;
    #pragma unroll 1
    for (int tl = tl0; tl < 64; ++tl) {
        const int t = r0 + tl;
        const float potv = potL[tl * UU + u];

        float a[16];
        #pragma unroll
        for (int i = 0; i < 16; ++i) a[i] = s[i] + cc[i];

        // first-occurrence argmax: pairwise tree, right wins only if strictly >
        float v8[8]; int i8[8];
        #pragma unroll
        for (int i = 0; i < 8; ++i) {
            const bool c = a[2*i+1] > a[2*i];
            v8[i] = c ? a[2*i+1] : a[2*i];
            i8[i] = c ? (2*i+1) : (2*i);
        }
        float v4[4]; int i4[4];
        #pragma unroll
        for (int i = 0; i < 4; ++i) {
            const bool c = v8[2*i+1] > v8[2*i];
            v4[i] = c ? v8[2*i+1] : v8[2*i];
            i4[i] = c ? i8[2*i+1] : i8[2*i];
        }
        float v2[2]; int i2[2];
        #pragma unroll
        for (int i = 0; i < 2; ++i) {
            const bool c = v4[2*i+1] > v4[2*i];
            v2[i] = c ? v4[2*i+1] : v4[2*i];
            i2[i] = c ? i4[2*i+1] : i4[2*i];
        }
        const bool cf = v2[1] > v2[0];
        const float pv = cf ? v2[1] : v2[0];
        const int pidx = hbase + (cf ? i2[1] : i2[0]);

        const float opv = __shfl_xor(pv, 32, 64);
        const int   opi = __shfl_xor(pidx, 32, 64);
        const bool take = h ? (opv >= pv) : (opv > pv);   // tie -> lower half
        const int  mv   = take ? opi : pidx;
        const float mm  = fmaxf(pv, opv) + potv;

        if (h == 0) bb[(size_t)(t - 1) * UU + u] = (unsigned char)mv;
        orig = __shfl(orig, mv, 64);

        mbuf[u] = mm;
        const float4 x0 = *(const float4*)&mbuf[hbase + 0];
        const float4 x1 = *(const float4*)&mbuf[hbase + 4];
        const float4 x2 = *(const float4*)&mbuf[hbase + 8];
        const float4 x3 = *(const float4*)&mbuf[hbase + 12];
        s[0]=x0.x; s[1]=x0.y; s[2]=x0.z;  s[3]=x0.w;
        s[4]=x1.x; s[5]=x1.y; s[6]=x1.z;  s[7]=x1.w;
        s[8]=x2.x; s[9]=x2.y; s[10]=x2.z; s[11]=x2.w;
        s[12]=x3.x; s[13]=x3.y; s[14]=x3.z; s[15]=x3.w;
    }

    if (h == 0) Mg[(size_t)b * 1024 + w * UU + u] = (unsigned char)orig;
}

// ---------------------------------------------------------------------------
// Kernel 4: per-batch boundary walk over M + 32 parallel window backtracks.
// ---------------------------------------------------------------------------
__global__ __launch_bounds__(64) void vit_backtrack_kernel(
    const float* __restrict__ chk, const unsigned char* __restrict__ Mg,
    const unsigned char* __restrict__ bpg, int* __restrict__ out)
{
    __shared__ unsigned char Ml[1024];
    __shared__ int tagw[32];

    const int lane = threadIdx.x;
    const int b = blockIdx.x;

    ((int4*)Ml)[lane] = ((const int4*)(Mg + (size_t)b * 1024))[lane];

    // last_tag = argmax_u chk[b][32][u], smallest u on tie
    float fv = (lane < 32) ? chk[((size_t)b * 33 + 32) * UU + lane] : -INFINITY;
    int fi = lane & 31;
    #pragma unroll
    for (int mask = 16; mask >= 1; mask >>= 1) {
        const float ov = __shfl_xor(fv, mask, 64);
        const int oi = __shfl_xor(fi, mask, 64);
        if (ov > fv || (ov == fv && oi < fi)) { fv = ov; fi = oi; }
    }
    int bt = __shfl(fi, 0, 64);

    __syncthreads();
    #pragma unroll 1
    for (int w = 31; w >= 0; --w) {
        if (lane == 0) tagw[w] = bt;         // tag at t = 64w+63
        bt = Ml[w * 32 + bt];                // -> tag at 64(w-1)+63
    }
    __syncthreads();

    if (lane < 32) {
        const int w = lane;
        int tag = tagw[w];
        int t = w * 64 + 63;
        int* ob = out + (size_t)b * TT;
        const unsigned char* bb = bpg + (size_t)b * (TT - 1) * UU;
        ob[t] = tag;
        #pragma unroll 1
        for (; t >= w * 64 + 1; --t) {
            tag = bb[(size_t)(t - 1) * UU + tag];
            ob[t - 1] = tag;
        }
    }
}

// ---------------------------------------------------------------------------
extern "C" void kernel_launch(void* const* d_in, const int* in_sizes, int n_in,
                              void* d_out, int out_size, void* d_ws, size_t ws_size,
                              hipStream_t stream)
{
    const float* x     = (const float*)d_in[0];
    const float* K     = (const float*)d_in[1];
    const float* bias  = (const float*)d_in[2];
    const float* chain = (const float*)d_in[3];
    const float* lb    = (const float*)d_in[4];
    const float* rb    = (const float*)d_in[5];
    int* out = (int*)d_out;

    float* pot = (float*)d_ws;                          // 16 MB
    float* chk = pot + (size_t)BB * TT * UU;            // 64*33*32 floats = 264 KB
    unsigned char* Mg  = (unsigned char*)(chk + (size_t)BB * 33 * UU);  // 64 KB
    unsigned char* bpg = Mg + (size_t)BB * 32 * UU;     // 64*2047*32 = 4 MB

    potentials_kernel<<<1024, 256, 0, stream>>>(x, K, bias, lb, rb, pot);
    vit_values_kernel<<<BB / 2, 64, 0, stream>>>(pot, chain, chk);
    vit_window_kernel<<<dim3(32, BB), 64, 0, stream>>>(pot, chain, chk, Mg, bpg);
    vit_backtrack_kernel<<<BB, 64, 0, stream>>>(chk, Mg, bpg, out);
}

// Round 4
// 562.260 us; speedup vs baseline: 2.4211x; 1.0294x over previous
//
#include <hip/hip_runtime.h>
#include <hip/hip_bf16.h>
#include <cstdint>

#define BB 64
#define TT 2048
#define FD 256
#define UU 32

// ---------------------------------------------------------------------------
// Kernel 1: pot[b,t,u] = dot(x[b,t,:], K[:,u]) + bias[u] (+ boundaries)
// x rows read from global (broadcast within u-group, L1-served, each byte
// fetched once). K transposed in LDS [u][f] (pad 260) -> one b128 per f-quad.
// 32-row tiles, 4 rows/thread, strict ascending-f accumulation per row
// (bit-identical op order to previous passing version).
// ---------------------------------------------------------------------------
__global__ __launch_bounds__(256, 4) void potentials_kernel(
    const float* __restrict__ x, const float* __restrict__ K,
    const float* __restrict__ bias, const float* __restrict__ lb,
    const float* __restrict__ rb, float* __restrict__ pot)
{
    __shared__ float Kt[UU * 260];   // 33 KB, [u][f] padded

    const int tid = threadIdx.x;
    const int u = tid & 31;
    const int g = tid >> 5;               // 0..7

    for (int idx = tid; idx < FD * UU; idx += 256) {
        const int f = idx >> 5;
        const int uu = idx & 31;
        Kt[uu * 260 + f] = K[idx];        // K is [f][u] row-major
    }
    __syncthreads();

    const float bu = bias[u];
    const float lu = lb[u];
    const float ru = rb[u];

    const int tiles = (BB * TT) / 32;     // 4096
    for (int tile = blockIdx.x; tile < tiles; tile += gridDim.x) {
        const int row0 = tile * 32;
        const float* x0 = x + (size_t)(row0 + g) * FD;

        float acc0 = 0.f, acc1 = 0.f, acc2 = 0.f, acc3 = 0.f;
        #pragma unroll 4
        for (int f = 0; f < FD; f += 4) {
            const float4 kq = *(const float4*)&Kt[u * 260 + f];
            const float4 xa = *(const float4*)(x0 + f);
            const float4 xb = *(const float4*)(x0 + 8 * FD + f);
            const float4 xc = *(const float4*)(x0 + 16 * FD + f);
            const float4 xd = *(const float4*)(x0 + 24 * FD + f);
            acc0 += xa.x * kq.x; acc0 += xa.y * kq.y; acc0 += xa.z * kq.z; acc0 += xa.w * kq.w;
            acc1 += xb.x * kq.x; acc1 += xb.y * kq.y; acc1 += xb.z * kq.z; acc1 += xb.w * kq.w;
            acc2 += xc.x * kq.x; acc2 += xc.y * kq.y; acc2 += xc.z * kq.z; acc2 += xc.w * kq.w;
            acc3 += xd.x * kq.x; acc3 += xd.y * kq.y; acc3 += xd.z * kq.z; acc3 += xd.w * kq.w;
        }

        const int r0 = row0 + g;
        const int r1 = r0 + 8;
        const int r2 = r0 + 16;
        const int r3 = r0 + 24;
        const int t0 = r0 & (TT - 1), t1 = r1 & (TT - 1);
        const int t2 = r2 & (TT - 1), t3 = r3 & (TT - 1);
        pot[(size_t)r0 * UU + u] = acc0 + bu + (t0 == 0 ? lu : 0.f) + (t0 == TT - 1 ? ru : 0.f);
        pot[(size_t)r1 * UU + u] = acc1 + bu + (t1 == 0 ? lu : 0.f) + (t1 == TT - 1 ? ru : 0.f);
        pot[(size_t)r2 * UU + u] = acc2 + bu + (t2 == 0 ? lu : 0.f) + (t2 == TT - 1 ? ru : 0.f);
        pot[(size_t)r3 * UU + u] = acc3 + bu + (t3 == 0 ? lu : 0.f) + (t3 == TT - 1 ? ru : 0.f);
    }
}

// ---------------------------------------------------------------------------
// quad_perm [1,0,3,2]: swap adjacent lane pairs via DPP (VALU pipe, no LDS).
// ---------------------------------------------------------------------------
__device__ __forceinline__ float quad_swap(float v) {
    const int i = __float_as_int(v);
    const int r = __builtin_amdgcn_update_dpp(i, i, 0xB1, 0xF, 0xF, true);
    return __int_as_float(r);
}

// ---------------------------------------------------------------------------
// Kernel 2: values-only serial forward, latency-optimized v2.
// One batch per wave (64 blocks). Lane = (u = lane>>1, q = lane&1): each lane
// holds a 16-deep v-half column cc[i] = chain[16q+i][u], state half s[16].
// Step: 16 adds + exact max tree + DPP pair-combine + pot, then one LDS
// write + 4 broadcast b128 reads (evens: mbuf[0..15], odds: mbuf[16..31]).
// Values bit-identical to previous rounds (exact max reassociation only).
// Checkpoints: chk[b][w][u] = state at t = 64w-1 (w=1..31), chk[b][32] = t=2047.
// ---------------------------------------------------------------------------
__global__ __launch_bounds__(64) void vit_values_kernel(
    const float* __restrict__ pot, const float* __restrict__ chain,
    float* __restrict__ chk)
{
    __shared__ __align__(16) float mbuf[32];

    const int lane = threadIdx.x;
    const int u = lane >> 1;
    const int q = lane & 1;
    const int qb = 16 * q;
    const int b = blockIdx.x;
    const float* pb = pot + (size_t)b * TT * UU;

    float cc[16];
    #pragma unroll
    for (int i = 0; i < 16; ++i) cc[i] = chain[(qb + i) * UU + u];

    float s[16];
    {
        const float4* s0 = (const float4*)(pb + qb);
        #pragma unroll
        for (int k = 0; k < 4; ++k) {
            const float4 v = s0[k];
            s[4*k+0] = v.x; s[4*k+1] = v.y; s[4*k+2] = v.z; s[4*k+3] = v.w;
        }
    }

    auto step = [&](float potv, int t) {
        float a[16];
        #pragma unroll
        for (int i = 0; i < 16; ++i) a[i] = s[i] + cc[i];
        float m8[8];
        #pragma unroll
        for (int i = 0; i < 8; ++i) m8[i] = fmaxf(a[2*i], a[2*i+1]);
        float m4[4];
        #pragma unroll
        for (int i = 0; i < 4; ++i) m4[i] = fmaxf(m8[2*i], m8[2*i+1]);
        const float pm = fmaxf(fmaxf(m4[0], m4[1]), fmaxf(m4[2], m4[3]));
        const float om = quad_swap(pm);          // other half's partial max
        const float mm = fmaxf(pm, om) + potv;   // exact max, single rounding

        mbuf[u] = mm;                            // both q-lanes write same value

        if ((t & 63) == 63)
            chk[((size_t)b * 33 + ((t >> 6) + 1)) * UU + u] = mm;

        const float4 x0 = *(const float4*)&mbuf[qb + 0];
        const float4 x1 = *(const float4*)&mbuf[qb + 4];
        const float4 x2 = *(const float4*)&mbuf[qb + 8];
        const float4 x3 = *(const float4*)&mbuf[qb + 12];
        s[0]=x0.x;  s[1]=x0.y;  s[2]=x0.z;  s[3]=x0.w;
        s[4]=x1.x;  s[5]=x1.y;  s[6]=x1.z;  s[7]=x1.w;
        s[8]=x2.x;  s[9]=x2.y;  s[10]=x2.z; s[11]=x2.w;
        s[12]=x3.x; s[13]=x3.y; s[14]=x3.z; s[15]=x3.w;
    };

    float pr[8], pn[8];
    #pragma unroll
    for (int j = 0; j < 8; ++j) pr[j] = pb[(1 + j) * UU + u];

    #pragma unroll 1
    for (int g = 0; g < 255; ++g) {
        #pragma unroll
        for (int j = 0; j < 8; ++j) {
            int tp = 9 + 8 * g + j;
            if (tp > TT - 1) tp = TT - 1;
            pn[j] = pb[tp * UU + u];
        }
        const int t0 = 1 + 8 * g;
        #pragma unroll
        for (int j = 0; j < 8; ++j)
            step(pr[j], t0 + j);
        #pragma unroll
        for (int j = 0; j < 8; ++j) pr[j] = pn[j];
    }
    // tail: t = 2041..2047 (includes final checkpoint wck = 32 at t = 2047)
    #pragma unroll
    for (int j = 0; j < 7; ++j)
        step(pr[j], 2041 + j);
}

// ---------------------------------------------------------------------------
// Kernel 3: parallel window recompute. Block (w, b): steps t in
// [max(1,64w), 64w+64) from bit-exact checkpoint; emits bp bytes (global) and
// survivor map M[w][u] = tag at window start for best path ending (64w+63, u).
// ---------------------------------------------------------------------------
__global__ __launch_bounds__(64) void vit_window_kernel(
    const float* __restrict__ pot, const float* __restrict__ chain,
    const float* __restrict__ chk, unsigned char* __restrict__ Mg,
    unsigned char* __restrict__ bpg)
{
    __shared__ float potL[64 * 32];   // 8 KB: pot rows 64w .. 64w+63
    __shared__ float mbuf[32];

    const int lane = threadIdx.x;
    const int u = lane & 31;
    const int h = lane >> 5;
    const int hbase = 16 * h;
    const int w = blockIdx.x;
    const int b = blockIdx.y;
    const float* pb = pot + (size_t)b * TT * UU;
    const int r0 = 64 * w;

    {
        const float4* src = (const float4*)(pb + (size_t)r0 * UU);
        float4* dst = (float4*)potL;
        #pragma unroll
        for (int k = 0; k < 8; ++k) dst[lane + 64 * k] = src[lane + 64 * k];
    }
    __syncthreads();

    float cc[16];
    #pragma unroll
    for (int i = 0; i < 16; ++i) cc[i] = chain[(hbase + i) * UU + u];

    float s[16];
    if (w == 0) {
        #pragma unroll
        for (int i = 0; i < 16; ++i) s[i] = potL[hbase + i];          // state t=0
    } else {
        #pragma unroll
        for (int i = 0; i < 16; ++i) s[i] = chk[((size_t)b * 33 + w) * UU + hbase + i];
    }

    int orig = u;
    unsigned char* bb = bpg + (size_t)b * (TT - 1) * UU;

    const int tl0 = (w == 0) ? 1 : 0;
    #pragma unroll 1
    for (int tl = tl0; tl < 64; ++tl) {
        const int t = r0 + tl;
        const float potv = potL[tl * UU + u];

        float a[16];
        #pragma unroll
        for (int i = 0; i < 16; ++i) a[i] = s[i] + cc[i];

        // first-occurrence argmax: pairwise tree, right wins only if strictly >
        float v8[8]; int i8[8];
        #pragma unroll
        for (int i = 0; i < 8; ++i) {
            const bool c = a[2*i+1] > a[2*i];
            v8[i] = c ? a[2*i+1] : a[2*i];
            i8[i] = c ? (2*i+1) : (2*i);
        }
        float v4[4]; int i4[4];
        #pragma unroll
        for (int i = 0; i < 4; ++i) {
            const bool c = v8[2*i+1] > v8[2*i];
            v4[i] = c ? v8[2*i+1] : v8[2*i];
            i4[i] = c ? i8[2*i+1] : i8[2*i];
        }
        float v2[2]; int i2[2];
        #pragma unroll
        for (int i = 0; i < 2; ++i) {
            const bool c = v4[2*i+1] > v4[2*i];
            v2[i] = c ? v4[2*i+1] : v4[2*i];
            i2[i] = c ? i4[2*i+1] : i4[2*i];
        }
        const bool cf = v2[1] > v2[0];
        const float pv = cf ? v2[1] : v2[0];
        const int pidx = hbase + (cf ? i2[1] : i2[0]);

        const float opv = __shfl_xor(pv, 32, 64);
        const int   opi = __shfl_xor(pidx, 32, 64);
        const bool take = h ? (opv >= pv) : (opv > pv);   // tie -> lower half
        const int  mv   = take ? opi : pidx;
        const float mm  = fmaxf(pv, opv) + potv;

        if (h == 0) bb[(size_t)(t - 1) * UU + u] = (unsigned char)mv;
        orig = __shfl(orig, mv, 64);

        mbuf[u] = mm;
        const float4 x0 = *(const float4*)&mbuf[hbase + 0];
        const float4 x1 = *(const float4*)&mbuf[hbase + 4];
        const float4 x2 = *(const float4*)&mbuf[hbase + 8];
        const float4 x3 = *(const float4*)&mbuf[hbase + 12];
        s[0]=x0.x; s[1]=x0.y; s[2]=x0.z;  s[3]=x0.w;
        s[4]=x1.x; s[5]=x1.y; s[6]=x1.z;  s[7]=x1.w;
        s[8]=x2.x; s[9]=x2.y; s[10]=x2.z; s[11]=x2.w;
        s[12]=x3.x; s[13]=x3.y; s[14]=x3.z; s[15]=x3.w;
    }

    if (h == 0) Mg[(size_t)b * 1024 + w * UU + u] = (unsigned char)orig;
}

// ---------------------------------------------------------------------------
// Kernel 4: per-batch boundary walk over M + 32 parallel window backtracks.
// ---------------------------------------------------------------------------
__global__ __launch_bounds__(64) void vit_backtrack_kernel(
    const float* __restrict__ chk, const unsigned char* __restrict__ Mg,
    const unsigned char* __restrict__ bpg, int* __restrict__ out)
{
    __shared__ unsigned char Ml[1024];
    __shared__ int tagw[32];

    const int lane = threadIdx.x;
    const int b = blockIdx.x;

    ((int4*)Ml)[lane] = ((const int4*)(Mg + (size_t)b * 1024))[lane];

    // last_tag = argmax_u chk[b][32][u], smallest u on tie
    float fv = (lane < 32) ? chk[((size_t)b * 33 + 32) * UU + lane] : -INFINITY;
    int fi = lane & 31;
    #pragma unroll
    for (int mask = 16; mask >= 1; mask >>= 1) {
        const float ov = __shfl_xor(fv, mask, 64);
        const int oi = __shfl_xor(fi, mask, 64);
        if (ov > fv || (ov == fv && oi < fi)) { fv = ov; fi = oi; }
    }
    int bt = __shfl(fi, 0, 64);

    __syncthreads();
    #pragma unroll 1
    for (int w = 31; w >= 0; --w) {
        if (lane == 0) tagw[w] = bt;         // tag at t = 64w+63
        bt = Ml[w * 32 + bt];                // -> tag at 64(w-1)+63
    }
    __syncthreads();

    if (lane < 32) {
        const int w = lane;
        int tag = tagw[w];
        int t = w * 64 + 63;
        int* ob = out + (size_t)b * TT;
        const unsigned char* bb = bpg + (size_t)b * (TT - 1) * UU;
        ob[t] = tag;
        #pragma unroll 1
        for (; t >= w * 64 + 1; --t) {
            tag = bb[(size_t)(t - 1) * UU + tag];
            ob[t - 1] = tag;
        }
    }
}

// ---------------------------------------------------------------------------
extern "C" void kernel_launch(void* const* d_in, const int* in_sizes, int n_in,
                              void* d_out, int out_size, void* d_ws, size_t ws_size,
                              hipStream_t stream)
{
    const float* x     = (const float*)d_in[0];
    const float* K     = (const float*)d_in[1];
    const float* bias  = (const float*)d_in[2];
    const float* chain = (const float*)d_in[3];
    const float* lb    = (const float*)d_in[4];
    const float* rb    = (const float*)d_in[5];
    int* out = (int*)d_out;

    float* pot = (float*)d_ws;                          // 16 MB
    float* chk = pot + (size_t)BB * TT * UU;            // 64*33*32 floats = 264 KB
    unsigned char* Mg  = (unsigned char*)(chk + (size_t)BB * 33 * UU);  // 64 KB
    unsigned char* bpg = Mg + (size_t)BB * 32 * UU;     // 64*2047*32 = 4 MB

    potentials_kernel<<<1024, 256, 0, stream>>>(x, K, bias, lb, rb, pot);
    vit_values_kernel<<<BB, 64, 0, stream>>>(pot, chain, chk);
    vit_window_kernel<<<dim3(32, BB), 64, 0, stream>>>(pot, chain, chk, Mg, bpg);
    vit_backtrack_kernel<<<BB, 64, 0, stream>>>(chk, Mg, bpg, out);
}

// Round 5
// 532.078 us; speedup vs baseline: 2.5584x; 1.0567x over previous
//
#include <hip/hip_runtime.h>
#include <hip/hip_bf16.h>
#include <cstdint>

#define BB 64
#define TT 2048
#define FD 256
#define UU 32

// ---------------------------------------------------------------------------
// Kernel 1: pot[b,t,u] = dot(x[b,t,:], K[:,u]) + bias[u] (+ boundaries)
// One wave per block. Both operands in LDS, XOR-swizzled quad layout:
// element quad q of row r lives at slot (q ^ (r&7)) -> every ds_read_b128 is
// conflict-free (8 distinct bank-groups x 8-way same-address broadcast).
// Thread (ug=tid&7, rg=tid>>3) computes rows {rg+8i} x cols {ug+8m}, i,m<4:
// 2 B of LDS per FMA. Ascending-f sequential accumulation (bit-identical pot).
// ---------------------------------------------------------------------------
__global__ __launch_bounds__(64) void potentials_kernel(
    const float* __restrict__ x, const float* __restrict__ K,
    const float* __restrict__ bias, const float* __restrict__ lb,
    const float* __restrict__ rb, float* __restrict__ pot)
{
    __shared__ __align__(16) float lds[16384];   // 64 KB total
    float* xs = lds;            // [32 rows][256 f], swizzled quads
    float* Kt = lds + 8192;     // [32 u]  [256 f], swizzled quads

    const int tid = threadIdx.x;
    const int ug = tid & 7;
    const int rg = tid >> 3;

    // Stage K (once): K is [f][u] row-major -> Kt[u][f] swizzled.
    for (int j = 0; j < 128; ++j) {
        const int e = j * 64 + tid;
        const int f = e >> 5;
        const int u = e & 31;
        Kt[u * 256 + (((f >> 2) ^ (u & 7)) << 2) + (f & 3)] = K[e];
    }

    float bu[4], lu4[4], ru4[4];
    #pragma unroll
    for (int m = 0; m < 4; ++m) {
        bu[m]  = bias[ug + 8 * m];
        lu4[m] = lb[ug + 8 * m];
        ru4[m] = rb[ug + 8 * m];
    }

    const int tiles = (BB * TT) / 32;     // 4096
    for (int tile = blockIdx.x; tile < tiles; tile += gridDim.x) {
        const int row0 = tile * 32;
        __syncthreads();                  // protect xs from previous readers
        #pragma unroll 4
        for (int k = 0; k < 32; ++k) {
            const float4 v = *(const float4*)(x + (size_t)(row0 + k) * FD + tid * 4);
            *(float4*)&xs[k * 256 + ((tid ^ (k & 7)) << 2)] = v;
        }
        __syncthreads();

        float acc[4][4];
        #pragma unroll
        for (int i = 0; i < 4; ++i)
            #pragma unroll
            for (int m = 0; m < 4; ++m) acc[i][m] = 0.f;

        #pragma unroll 4
        for (int q = 0; q < 64; ++q) {
            float4 xq[4], kq[4];
            #pragma unroll
            for (int i = 0; i < 4; ++i)
                xq[i] = *(const float4*)&xs[(rg + 8 * i) * 256 + ((q ^ rg) << 2)];
            #pragma unroll
            for (int m = 0; m < 4; ++m)
                kq[m] = *(const float4*)&Kt[(ug + 8 * m) * 256 + ((q ^ ug) << 2)];
            #pragma unroll
            for (int i = 0; i < 4; ++i)
                #pragma unroll
                for (int m = 0; m < 4; ++m) {
                    acc[i][m] += xq[i].x * kq[m].x;
                    acc[i][m] += xq[i].y * kq[m].y;
                    acc[i][m] += xq[i].z * kq[m].z;
                    acc[i][m] += xq[i].w * kq[m].w;
                }
        }

        #pragma unroll
        for (int i = 0; i < 4; ++i) {
            const int row = row0 + rg + 8 * i;
            const int t = row & (TT - 1);
            #pragma unroll
            for (int m = 0; m < 4; ++m) {
                pot[(size_t)row * UU + ug + 8 * m] =
                    acc[i][m] + bu[m] + (t == 0 ? lu4[m] : 0.f)
                              + (t == TT - 1 ? ru4[m] : 0.f);
            }
        }
    }
}

// ---------------------------------------------------------------------------
// quad_perm [1,0,3,2]: swap adjacent lane pairs via DPP (VALU pipe, no LDS).
// ---------------------------------------------------------------------------
__device__ __forceinline__ float quad_swap(float v) {
    const int i = __float_as_int(v);
    const int r = __builtin_amdgcn_update_dpp(i, i, 0xB1, 0xF, 0xF, true);
    return __int_as_float(r);
}

// ---------------------------------------------------------------------------
// Kernel 2: values-only serial forward (unchanged from round 4 — 195 us,
// latency-bound on the LDS write->read broadcast roundtrip).
// ---------------------------------------------------------------------------
__global__ __launch_bounds__(64) void vit_values_kernel(
    const float* __restrict__ pot, const float* __restrict__ chain,
    float* __restrict__ chk)
{
    __shared__ __align__(16) float mbuf[32];

    const int lane = threadIdx.x;
    const int u = lane >> 1;
    const int q = lane & 1;
    const int qb = 16 * q;
    const int b = blockIdx.x;
    const float* pb = pot + (size_t)b * TT * UU;

    float cc[16];
    #pragma unroll
    for (int i = 0; i < 16; ++i) cc[i] = chain[(qb + i) * UU + u];

    float s[16];
    {
        const float4* s0 = (const float4*)(pb + qb);
        #pragma unroll
        for (int k = 0; k < 4; ++k) {
            const float4 v = s0[k];
            s[4*k+0] = v.x; s[4*k+1] = v.y; s[4*k+2] = v.z; s[4*k+3] = v.w;
        }
    }

    auto step = [&](float potv, int t) {
        float a[16];
        #pragma unroll
        for (int i = 0; i < 16; ++i) a[i] = s[i] + cc[i];
        float m8[8];
        #pragma unroll
        for (int i = 0; i < 8; ++i) m8[i] = fmaxf(a[2*i], a[2*i+1]);
        float m4[4];
        #pragma unroll
        for (int i = 0; i < 4; ++i) m4[i] = fmaxf(m8[2*i], m8[2*i+1]);
        const float pm = fmaxf(fmaxf(m4[0], m4[1]), fmaxf(m4[2], m4[3]));
        const float om = quad_swap(pm);          // other half's partial max
        const float mm = fmaxf(pm, om) + potv;   // exact max, single rounding

        mbuf[u] = mm;                            // both q-lanes write same value

        if ((t & 63) == 63)
            chk[((size_t)b * 33 + ((t >> 6) + 1)) * UU + u] = mm;

        const float4 x0 = *(const float4*)&mbuf[qb + 0];
        const float4 x1 = *(const float4*)&mbuf[qb + 4];
        const float4 x2 = *(const float4*)&mbuf[qb + 8];
        const float4 x3 = *(const float4*)&mbuf[qb + 12];
        s[0]=x0.x;  s[1]=x0.y;  s[2]=x0.z;  s[3]=x0.w;
        s[4]=x1.x;  s[5]=x1.y;  s[6]=x1.z;  s[7]=x1.w;
        s[8]=x2.x;  s[9]=x2.y;  s[10]=x2.z; s[11]=x2.w;
        s[12]=x3.x; s[13]=x3.y; s[14]=x3.z; s[15]=x3.w;
    };

    float pr[8], pn[8];
    #pragma unroll
    for (int j = 0; j < 8; ++j) pr[j] = pb[(1 + j) * UU + u];

    #pragma unroll 1
    for (int g = 0; g < 255; ++g) {
        #pragma unroll
        for (int j = 0; j < 8; ++j) {
            int tp = 9 + 8 * g + j;
            if (tp > TT - 1) tp = TT - 1;
            pn[j] = pb[tp * UU + u];
        }
        const int t0 = 1 + 8 * g;
        #pragma unroll
        for (int j = 0; j < 8; ++j)
            step(pr[j], t0 + j);
        #pragma unroll
        for (int j = 0; j < 8; ++j) pr[j] = pn[j];
    }
    // tail: t = 2041..2047 (includes final checkpoint wck = 32 at t = 2047)
    #pragma unroll
    for (int j = 0; j < 7; ++j)
        step(pr[j], 2041 + j);
}

// ---------------------------------------------------------------------------
// Kernel 3: parallel window recompute (unchanged). Block (w, b): steps t in
// [max(1,64w), 64w+64) from bit-exact checkpoint; emits bp bytes (global) and
// survivor map M[w][u] = tag at window start for best path ending (64w+63, u).
// ---------------------------------------------------------------------------
__global__ __launch_bounds__(64) void vit_window_kernel(
    const float* __restrict__ pot, const float* __restrict__ chain,
    const float* __restrict__ chk, unsigned char* __restrict__ Mg,
    unsigned char* __restrict__ bpg)
{
    __shared__ float potL[64 * 32];   // 8 KB: pot rows 64w .. 64w+63
    __shared__ float mbuf[32];

    const int lane = threadIdx.x;
    const int u = lane & 31;
    const int h = lane >> 5;
    const int hbase = 16 * h;
    const int w = blockIdx.x;
    const int b = blockIdx.y;
    const float* pb = pot + (size_t)b * TT * UU;
    const int r0 = 64 * w;

    {
        const float4* src = (const float4*)(pb + (size_t)r0 * UU);
        float4* dst = (float4*)potL;
        #pragma unroll
        for (int k = 0; k < 8; ++k) dst[lane + 64 * k] = src[lane + 64 * k];
    }
    __syncthreads();

    float cc[16];
    #pragma unroll
    for (int i = 0; i < 16; ++i) cc[i] = chain[(hbase + i) * UU + u];

    float s[16];
    if (w == 0) {
        #pragma unroll
        for (int i = 0; i < 16; ++i) s[i] = potL[hbase + i];          // state t=0
    } else {
        #pragma unroll
        for (int i = 0; i < 16; ++i) s[i] = chk[((size_t)b * 33 + w) * UU + hbase + i];
    }

    int orig = u;
    unsigned char* bb = bpg + (size_t)b * (TT - 1) * UU;

    const int tl0 = (w == 0) ? 1 : 0;
    #pragma unroll 1
    for (int tl = tl0; tl < 64; ++tl) {
        const int t = r0 + tl;
        const float potv = potL[tl * UU + u];

        float a[16];
        #pragma unroll
        for (int i = 0; i < 16; ++i) a[i] = s[i] + cc[i];

        // first-occurrence argmax: pairwise tree, right wins only if strictly >
        float v8[8]; int i8[8];
        #pragma unroll
        for (int i = 0; i < 8; ++i) {
            const bool c = a[2*i+1] > a[2*i];
            v8[i] = c ? a[2*i+1] : a[2*i];
            i8[i] = c ? (2*i+1) : (2*i);
        }
        float v4[4]; int i4[4];
        #pragma unroll
        for (int i = 0; i < 4; ++i) {
            const bool c = v8[2*i+1] > v8[2*i];
            v4[i] = c ? v8[2*i+1] : v8[2*i];
            i4[i] = c ? i8[2*i+1] : i8[2*i];
        }
        float v2[2]; int i2[2];
        #pragma unroll
        for (int i = 0; i < 2; ++i) {
            const bool c = v4[2*i+1] > v4[2*i];
            v2[i] = c ? v4[2*i+1] : v4[2*i];
            i2[i] = c ? i4[2*i+1] : i4[2*i];
        }
        const bool cf = v2[1] > v2[0];
        const float pv = cf ? v2[1] : v2[0];
        const int pidx = hbase + (cf ? i2[1] : i2[0]);

        const float opv = __shfl_xor(pv, 32, 64);
        const int   opi = __shfl_xor(pidx, 32, 64);
        const bool take = h ? (opv >= pv) : (opv > pv);   // tie -> lower half
        const int  mv   = take ? opi : pidx;
        const float mm  = fmaxf(pv, opv) + potv;

        if (h == 0) bb[(size_t)(t - 1) * UU + u] = (unsigned char)mv;
        orig = __shfl(orig, mv, 64);

        mbuf[u] = mm;
        const float4 x0 = *(const float4*)&mbuf[hbase + 0];
        const float4 x1 = *(const float4*)&mbuf[hbase + 4];
        const float4 x2 = *(const float4*)&mbuf[hbase + 8];
        const float4 x3 = *(const float4*)&mbuf[hbase + 12];
        s[0]=x0.x; s[1]=x0.y; s[2]=x0.z;  s[3]=x0.w;
        s[4]=x1.x; s[5]=x1.y; s[6]=x1.z;  s[7]=x1.w;
        s[8]=x2.x; s[9]=x2.y; s[10]=x2.z; s[11]=x2.w;
        s[12]=x3.x; s[13]=x3.y; s[14]=x3.z; s[15]=x3.w;
    }

    if (h == 0) Mg[(size_t)b * 1024 + w * UU + u] = (unsigned char)orig;
}

// ---------------------------------------------------------------------------
// Kernel 4: per-batch backtrack. bp slice (65504 B) staged into LDS with
// coalesced b128 loads, so the 63-step window walks hit LDS (~60 cyc) instead
// of cross-XCD HBM (~900 cyc). Boundary walk reads Mg via uniform global
// loads (L2, ~32 x 200 cyc).
// ---------------------------------------------------------------------------
__global__ __launch_bounds__(64) void vit_backtrack_kernel(
    const float* __restrict__ chk, const unsigned char* __restrict__ Mg,
    const unsigned char* __restrict__ bpg, int* __restrict__ out)
{
    __shared__ __align__(16) unsigned char bp[(TT - 1) * UU];   // 65504 B

    const int lane = threadIdx.x;
    const int b = blockIdx.x;
    const unsigned char* bb = bpg + (size_t)b * (TT - 1) * UU;

    // stage bp: 4094 int4s
    #pragma unroll 4
    for (int i = 0; i < 64; ++i) {
        const int idx = i * 64 + lane;
        if (idx < 4094)
            ((int4*)bp)[idx] = ((const int4*)bb)[idx];
    }

    // last_tag = argmax_u chk[b][32][u], smallest u on tie
    float fv = (lane < 32) ? chk[((size_t)b * 33 + 32) * UU + lane] : -INFINITY;
    int fi = lane & 31;
    #pragma unroll
    for (int mask = 16; mask >= 1; mask >>= 1) {
        const float ov = __shfl_xor(fv, mask, 64);
        const int oi = __shfl_xor(fi, mask, 64);
        if (ov > fv || (ov == fv && oi < fi)) { fv = ov; fi = oi; }
    }
    int bt = __shfl(fi, 0, 64);

    // boundary walk over Mg (uniform addresses -> broadcast global loads);
    // lane w captures its window's end tag in a register.
    int my_btag = 0;
    #pragma unroll 1
    for (int w = 31; w >= 0; --w) {
        if (lane == w) my_btag = bt;         // tag at t = 64w+63
        bt = Mg[(size_t)b * 1024 + w * 32 + bt];
    }

    __syncthreads();                         // bp staging visible

    if (lane < 32) {
        const int w = lane;
        int tag = my_btag;
        int t = w * 64 + 63;
        int* ob = out + (size_t)b * TT;
        ob[t] = tag;
        #pragma unroll 1
        for (; t >= w * 64 + 1; --t) {
            tag = bp[(t - 1) * UU + tag];
            ob[t - 1] = tag;
        }
    }
}

// ---------------------------------------------------------------------------
extern "C" void kernel_launch(void* const* d_in, const int* in_sizes, int n_in,
                              void* d_out, int out_size, void* d_ws, size_t ws_size,
                              hipStream_t stream)
{
    const float* x     = (const float*)d_in[0];
    const float* K     = (const float*)d_in[1];
    const float* bias  = (const float*)d_in[2];
    const float* chain = (const float*)d_in[3];
    const float* lb    = (const float*)d_in[4];
    const float* rb    = (const float*)d_in[5];
    int* out = (int*)d_out;

    float* pot = (float*)d_ws;                          // 16 MB
    float* chk = pot + (size_t)BB * TT * UU;            // 64*33*32 floats = 264 KB
    unsigned char* Mg  = (unsigned char*)(chk + (size_t)BB * 33 * UU);  // 64 KB
    unsigned char* bpg = Mg + (size_t)BB * 32 * UU;     // 64*2047*32 = 4 MB

    potentials_kernel<<<512, 64, 0, stream>>>(x, K, bias, lb, rb, pot);
    vit_values_kernel<<<BB, 64, 0, stream>>>(pot, chain, chk);
    vit_window_kernel<<<dim3(32, BB), 64, 0, stream>>>(pot, chain, chk, Mg, bpg);
    vit_backtrack_kernel<<<BB, 64, 0, stream>>>(chk, Mg, bpg, out);
}